// Round 8
// baseline (353.172 us; speedup 1.0000x reference)
//
#include <hip/hip_runtime.h>
#include <stdint.h>

#define HIDN 128
#define EMBN 32
#define PCAP 16   // pair bucket capacity (Poisson(2): P(>16)~5e-11)
#define NCAP 64   // node bucket capacity (Poisson(16): overflow ~0)

typedef __attribute__((ext_vector_type(8))) short bf16x8;
typedef __attribute__((ext_vector_type(4))) float f32x4;

// ---------- helpers ----------
__device__ __forceinline__ unsigned bf16r(float f) {   // fp32 -> bf16 bits, RNE
  unsigned u = __float_as_uint(f);
  return (u + 0x7FFFu + ((u >> 16) & 1u)) >> 16;
}
__device__ __forceinline__ unsigned pack2(float a, float b) {  // a -> low16, b -> high16
  return bf16r(a) | (bf16r(b) << 16);
}
__device__ __forceinline__ float blo(unsigned u) { return __uint_as_float(u << 16); }
__device__ __forceinline__ float bhi(unsigned u) { return __uint_as_float(u & 0xFFFF0000u); }
__device__ __forceinline__ float4 f4fma(float s, float4 a, float4 b) {
  return make_float4(fmaf(s, a.x, b.x), fmaf(s, a.y, b.y), fmaf(s, a.z, b.z), fmaf(s, a.w, b.w));
}
__device__ __forceinline__ float4 f4max0(float4 a) {
  return make_float4(fmaxf(a.x, 0.f), fmaxf(a.y, 0.f), fmaxf(a.z, 0.f), fmaxf(a.w, 0.f));
}

// ---------- prep1: Wq'=W2@Wq, Wk'=W2@Wk, biases, Wvsp/bvs (direct), dhd, wv2s ----------
__global__ __launch_bounds__(256) void k_prep1(
    const float* __restrict__ W2, const float* __restrict__ b2,
    const float* __restrict__ Wq, const float* __restrict__ Wk, const float* __restrict__ Wv,
    const float* __restrict__ Wq2, const float* __restrict__ Wk2, const float* __restrict__ Wv2,
    float* __restrict__ Wqp, float* __restrict__ Wkp,
    float* __restrict__ bqp, float* __restrict__ bkp,
    float* __restrict__ Wvsp, float* __restrict__ bvs,
    float* __restrict__ dhd, float* __restrict__ wv2s)
{
  const float rs = 0.17677669529663687f;  // 1/sqrt(32)
  int idx = blockIdx.x * 256 + threadIdx.x;
  if (idx < 8192) {
    int q = idx < 4096;
    int t = q ? idx : idx - 4096;
    int i = t >> 7, j = t & 127;
    const float* W = q ? Wq : Wk;
    float a = 0.f;
    for (int l = 0; l < HIDN; l++)
      a = fmaf(W2[i * HIDN + l], W[l * HIDN + j], a);
    (q ? Wqp : Wkp)[t] = a;
  } else if (idx < 8448) {
    int q = idx < 8320;
    int j = (q ? idx - 8192 : idx - 8320);
    const float* W = q ? Wq : Wk;
    float a = 0.f;
    for (int l = 0; l < HIDN; l++)
      a = fmaf(b2[l], W[l * HIDN + j], a);
    (q ? bqp : bkp)[j] = a;
  } else if (idx < 8576) {
    int t = idx - 8448;             // Wvsp[i*4+h] = sum_l W2[i][l] * sum_dh Wv[l][h*32+dh]
    int i = t >> 2, h = t & 3;
    float a = 0.f;
    for (int l = 0; l < HIDN; l++) {
      float s = 0.f;
      const float* wl = Wv + l * HIDN + h * 32;
      for (int dh = 0; dh < 32; dh++) s += wl[dh];
      a = fmaf(W2[i * HIDN + l], s, a);
    }
    Wvsp[t] = a;
  } else if (idx < 8580) {
    int h = idx - 8576;
    float a = 0.f;
    for (int l = 0; l < HIDN; l++) {
      float s = 0.f;
      const float* wl = Wv + l * HIDN + h * 32;
      for (int dh = 0; dh < 32; dh++) s += wl[dh];
      a = fmaf(b2[l], s, a);
    }
    bvs[h] = a;
  } else if (idx < 8584) {
    int h = idx - 8580;
    float d = 0.f, wsum = 0.f;
    for (int dh = 0; dh < 32; dh++) {
      d = fmaf(Wq2[h * 32 + dh], Wk2[h * 32 + dh], d);
      wsum += Wv2[h * 32 + dh];
    }
    dhd[h]  = d * rs;
    wv2s[h] = wsum;
  }
}

// ---------- prep2: MBpk fragments + c2th (needs Wqp/Wkp) ----------
__global__ __launch_bounds__(256) void k_prep2(
    const float* __restrict__ Wqp, const float* __restrict__ Wkp,
    const float* __restrict__ bqp,
    unsigned short* __restrict__ MBpk,  // [4][2][64][8] bf16 B-frags of M_h (scaled)
    float* __restrict__ c2th)           // [4][32]
{
  const float rs = 0.17677669529663687f;
  int idx = blockIdx.x * 256 + threadIdx.x;
  if (idx < 4096) {
    // B[k=(lane>>4)*8+jj][n=nb*16+(lane&15)], element jj of lane's short8
    int jj = idx & 7, lane = (idx >> 3) & 63, nb = (idx >> 9) & 1, h = idx >> 10;
    int k = (lane >> 4) * 8 + jj;
    int n = nb * 16 + (lane & 15);
    float a = 0.f;
    const float* wq = Wqp + k * HIDN + h * 32;
    const float* wk = Wkp + n * HIDN + h * 32;
    for (int j = 0; j < 32; j++) a = fmaf(wq[j], wk[j], a);
    MBpk[idx] = (unsigned short)bf16r(a * rs);
  } else if (idx < 4224) {
    int t = idx - 4096;
    int h = t >> 5, ip = t & 31;
    float a2 = 0.f;
    for (int j = 0; j < 32; j++)
      a2 = fmaf(bqp[h * 32 + j], Wkp[ip * HIDN + h * 32 + j], a2);
    c2th[h * 32 + ip] = a2 * rs;
  }
}

// ---------- K_front: edge MLP + slab-bucket scatters (pairs, nodes) ----------
__global__ __launch_bounds__(256, 4) void k_front(
    const float* __restrict__ x, const int* __restrict__ eidx, const float* __restrict__ ea,
    const float* __restrict__ W1, const float* __restrict__ b1,
    const float* __restrict__ Wvsp, const float* __restrict__ bvs,
    unsigned* __restrict__ embB, uint2* __restrict__ vsb,
    const int* __restrict__ e2e, int* __restrict__ pcnt, int* __restrict__ pbucket,
    const int* __restrict__ n2n, int* __restrict__ ncnt, float* __restrict__ nbucket,
    int E, int EE, int C, int N, int nEdgeB, int nPairB)
{
  int b = blockIdx.x;
  int tid = threadIdx.x;
  if (b < nEdgeB) {
    // ----- edge MLP path -----
    int e = b * 256 + tid;
    if (e >= E) return;
    int si = eidx[e], di = eidx[E + e];
    float xs = x[si], xd = x[di];

    const float4* b4  = (const float4*)b1;
    const float4* w0  = (const float4*)W1;         // row 0 (x_s)
    const float4* w1r = (const float4*)(W1 + 32);  // row 1 (x_d)
    float4 E0, E1, E2, E3, E4, E5, E6, E7;
#define INIT(i) E##i = f4fma(xs, w0[i], f4fma(xd, w1r[i], b4[i]));
    INIT(0) INIT(1) INIT(2) INIT(3) INIT(4) INIT(5) INIT(6) INIT(7)
#undef INIT
    const float4* ea4 = (const float4*)(ea + (size_t)e * 32);
#define ROW(c, wr) { const float4* w_ = (const float4*)(W1 + (size_t)(wr) * 32); \
  E0 = f4fma(c, w_[0], E0); E1 = f4fma(c, w_[1], E1); E2 = f4fma(c, w_[2], E2); E3 = f4fma(c, w_[3], E3); \
  E4 = f4fma(c, w_[4], E4); E5 = f4fma(c, w_[5], E5); E6 = f4fma(c, w_[6], E6); E7 = f4fma(c, w_[7], E7); }
#pragma unroll
    for (int rb = 0; rb < 8; rb++) {
      float4 v = ea4[rb];
      ROW(v.x, 2 + rb * 4 + 0)
      ROW(v.y, 2 + rb * 4 + 1)
      ROW(v.z, 2 + rb * 4 + 2)
      ROW(v.w, 2 + rb * 4 + 3)
    }
#undef ROW
    E0 = f4max0(E0); E1 = f4max0(E1); E2 = f4max0(E2); E3 = f4max0(E3);
    E4 = f4max0(E4); E5 = f4max0(E5); E6 = f4max0(E6); E7 = f4max0(E7);

    uint4 p0, p1, p2, p3;
    p0.x = pack2(E0.x, E0.y); p0.y = pack2(E0.z, E0.w); p0.z = pack2(E1.x, E1.y); p0.w = pack2(E1.z, E1.w);
    p1.x = pack2(E2.x, E2.y); p1.y = pack2(E2.z, E2.w); p1.z = pack2(E3.x, E3.y); p1.w = pack2(E3.z, E3.w);
    p2.x = pack2(E4.x, E4.y); p2.y = pack2(E4.z, E4.w); p2.z = pack2(E5.x, E5.y); p2.w = pack2(E5.z, E5.w);
    p3.x = pack2(E6.x, E6.y); p3.y = pack2(E6.z, E6.w); p3.z = pack2(E7.x, E7.y); p3.w = pack2(E7.z, E7.w);
    uint4* er = (uint4*)(embB + (size_t)e * 16);
    er[0] = p0; er[1] = p1; er[2] = p2; er[3] = p3;

    // vsum[h] = bvs + Wvsp.emb  -> bf16x4 (8 B)
    const float4* wv = (const float4*)Wvsp;
    float4 vs = *(const float4*)bvs;
#define VK(k) { vs = f4fma(E##k.x, wv[4*k+0], vs); vs = f4fma(E##k.y, wv[4*k+1], vs); \
                vs = f4fma(E##k.z, wv[4*k+2], vs); vs = f4fma(E##k.w, wv[4*k+3], vs); }
    VK(0) VK(1) VK(2) VK(3) VK(4) VK(5) VK(6) VK(7)
#undef VK
    vsb[e] = make_uint2(pack2(vs.x, vs.y), pack2(vs.z, vs.w));
  } else if (b < nEdgeB + nPairB) {
    // ----- pair scatter: column-major slab layout (slab = 1.6 MB, cache-resident) -----
    int p = (b - nEdgeB) * 256 + tid;
    if (p >= EE) return;
    int es = e2e[p], ed = e2e[EE + p];
    int pos = atomicAdd(&pcnt[ed], 1);
    if (pos < PCAP) pbucket[(size_t)pos * E + ed] = es;
  } else {
    // ----- node scatter: column-major slab layout (slab = 200 KB) -----
    int c = (b - nEdgeB - nPairB) * 256 + tid;
    if (c >= C) return;
    int ns = n2n[c], nd = n2n[C + c];
    if (nd >= N) return;              // never in practice (randint < N)
    float asv = x[ns];                // ns < N always
    int pos = atomicAdd(&ncnt[nd], 1);
    if (pos < NCAP) nbucket[(size_t)pos * N + nd] = asv;
  }
}

// ---------- K_back: MFMA qt-transform + pair softmax, and node softmax (merged) ----------
__global__ __launch_bounds__(256, 4) void k_back(
    const unsigned* __restrict__ embB, const unsigned short* __restrict__ MBpk,
    const uint2* __restrict__ vsb, const float* __restrict__ c2th,
    const int* __restrict__ pcnt, const int* __restrict__ pbucket,
    const int* __restrict__ ncnt, const float* __restrict__ nbucket,
    const float* __restrict__ x, const float* __restrict__ dhd, const float* __restrict__ wv2s,
    float* __restrict__ out0, float* __restrict__ out1,
    int E, int N, int nPairB)
{
  __shared__ float qtl[256 * 33];   // [e_local*4+h][33] fp32, pad 33 (bank-clean)
  int b = blockIdx.x;
  int tid = threadIdx.x;
  if (b < nPairB) {
    int wave = tid >> 6, lane = tid & 63;
    int e0 = b * 64;
    int we0 = e0 + wave * 16;

    // A fragment: A[m = lane&15][k = (lane>>4)*8 + j] = emb[we0 + m][k]
    union { uint4 u; bf16x8 bv; } af;
    af.u = *((const uint4*)(embB + ((size_t)(we0 + (lane & 15)) << 4)) + (lane >> 4));

#pragma unroll
    for (int h = 0; h < 4; h++) {
#pragma unroll
      for (int nb = 0; nb < 2; nb++) {
        union { uint4 u; bf16x8 bv; } bf;
        bf.u = *(const uint4*)(MBpk + (((h * 2 + nb) * 64 + lane) << 3));
        int col = nb * 16 + (lane & 15);
        float c2v = c2th[h * 32 + col];            // fold c2.emb_k into D (exact)
        f32x4 acc = {c2v, c2v, c2v, c2v};
        acc = __builtin_amdgcn_mfma_f32_16x16x32_bf16(af.bv, bf.bv, acc, 0, 0, 0);
        int rowb = wave * 16 + (lane >> 4) * 4;
#pragma unroll
        for (int r = 0; r < 4; r++)
          qtl[((rowb + r) * 4 + h) * 33 + col] = acc[r];
      }
    }
    __syncthreads();

    int e = e0 + (tid >> 2);
    if (e >= E) return;
    int h = tid & 3;
    const float* q = qtl + tid * 33;   // (e_local*4 + h) == tid

    int cnt = pcnt[e];
    cnt = cnt < PCAP ? cnt : PCAP;
    float den = 0.f, num = 0.f;
    for (int n = 0; n < cnt; n++) {
      int es = pbucket[(size_t)n * E + e];   // coalesced across the wave
      const uint4* ep = (const uint4*)(embB + ((size_t)es << 4));
      uint4 u0 = ep[0], u1 = ep[1], u2 = ep[2], u3 = ep[3];
      uint2 vu = vsb[es];
      unsigned vh = (h & 2) ? vu.y : vu.x;
      float vsv = (h & 1) ? bhi(vh) : blo(vh);
      float dot = 0.f;
#define DOT8(uu, base) \
      dot = fmaf(q[base + 0], blo(uu.x), dot); dot = fmaf(q[base + 1], bhi(uu.x), dot); \
      dot = fmaf(q[base + 2], blo(uu.y), dot); dot = fmaf(q[base + 3], bhi(uu.y), dot); \
      dot = fmaf(q[base + 4], blo(uu.z), dot); dot = fmaf(q[base + 5], bhi(uu.z), dot); \
      dot = fmaf(q[base + 6], blo(uu.w), dot); dot = fmaf(q[base + 7], bhi(uu.w), dot);
      DOT8(u0, 0) DOT8(u1, 8) DOT8(u2, 16) DOT8(u3, 24)
#undef DOT8
      float ex = __expf(dot);
      den += ex;
      num = fmaf(ex, vsv, num);
    }
    float r = num / (den + 1e-16f);
    r += __shfl_xor(r, 1);
    r += __shfl_xor(r, 2);
    if (h == 0) out1[e] = r * 0.0078125f;   // 1/128
  } else {
    // ----- node softmax path -----
    int idx = (b - nPairB) * 256 + tid;
    int nd = idx >> 2;
    if (nd >= N) return;
    int h = idx & 3;
    int cnt = ncnt[nd];
    cnt = cnt < NCAP ? cnt : NCAP;
    float xn = x[nd];
    float d = dhd[h];

    float amx = -3.4e38f, amn = 3.4e38f;
    for (int n = 0; n < cnt; n++) {
      float a = xn * nbucket[(size_t)n * N + nd];
      amx = fmaxf(amx, a); amn = fminf(amn, a);
    }
    float m = (d > 0.f) ? d * amx : d * amn;

    float den = 0.f, num = 0.f;
    for (int n = 0; n < cnt; n++) {
      float asv = nbucket[(size_t)n * N + nd];
      float ev = __expf(fmaf(xn * asv, d, -m));
      den += ev;
      num = fmaf(ev, asv, num);
    }
    float r = wv2s[h] * num / (den + 1e-16f);
    r += __shfl_xor(r, 1);
    r += __shfl_xor(r, 2);
    if (h == 0) out0[nd] = r * 0.0078125f;   // 1/128
  }
}

extern "C" void kernel_launch(void* const* d_in, const int* in_sizes, int n_in,
                              void* d_out, int out_size, void* d_ws, size_t ws_size,
                              hipStream_t stream)
{
  const float* x   = (const float*)d_in[0];
  const int*   eidx= (const int*)d_in[1];
  const float* ea  = (const float*)d_in[2];
  const int*   e2e = (const int*)d_in[3];
  const int*   n2n = (const int*)d_in[4];
  const float* W1  = (const float*)d_in[5];
  const float* b1  = (const float*)d_in[6];
  const float* W2  = (const float*)d_in[7];
  const float* b2  = (const float*)d_in[8];
  const float* Wq  = (const float*)d_in[9];
  const float* Wk  = (const float*)d_in[10];
  const float* Wv  = (const float*)d_in[11];
  const float* Wq2 = (const float*)d_in[12];
  const float* Wk2 = (const float*)d_in[13];
  const float* Wv2 = (const float*)d_in[14];

  const int N  = in_sizes[0];        // x is [N,1]
  const int E  = in_sizes[1] / 2;
  const int EE = in_sizes[3] / 2;
  const int C  = in_sizes[4] / 2;

  float* out0 = (float*)d_out;       // [N]
  float* out1 = (float*)d_out + N;   // [E]

  char* w = (char*)d_ws;
  size_t off = 0;
  auto alloc = [&](size_t bytes) -> char* {
    char* p = w + off;
    off += (bytes + 255) & ~(size_t)255;
    return p;
  };
  float* Wqp   = (float*)alloc(EMBN * HIDN * 4);
  float* Wkp   = (float*)alloc(EMBN * HIDN * 4);
  float* bqp   = (float*)alloc(HIDN * 4);
  float* bkp   = (float*)alloc(HIDN * 4);
  unsigned short* MBpk = (unsigned short*)alloc(4096 * 2);
  float* c2th  = (float*)alloc(4 * EMBN * 4);
  float* Wvsp  = (float*)alloc(EMBN * 4 * 4);
  float* bvs   = (float*)alloc(16);
  float* dhd   = (float*)alloc(16);
  float* wv2s  = (float*)alloc(16);
  unsigned* embB = (unsigned*)alloc((size_t)E * 16 * 4);     // 25.6 MB (bf16 emb)
  uint2* vsb   = (uint2*)alloc((size_t)E * 8);               // 3.2 MB (bf16 vsum)
  int*   pbucket = (int*)alloc((size_t)E * PCAP * 4);        // 25.6 MB, column-major slabs
  float* nbucket = (float*)alloc((size_t)N * NCAP * 4);      // 12.8 MB, column-major slabs
  char* zbase = w + off;                                     // --- zeroed block ---
  int*   pcnt  = (int*)alloc((size_t)E * 4);                 // 1.6 MB
  int*   ncnt  = (int*)alloc((size_t)N * 4);                 // 0.2 MB
  size_t zbytes = (size_t)((w + off) - zbase);

  const int nEdgeB = (E + 255) / 256;
  const int nPairB = (EE + 255) / 256;
  const int nNodeB = (C + 255) / 256;
  const int nPairMfmaB = (E + 63) / 64;
  const int nNodeSegB  = (N * 4 + 255) / 256;

  hipMemsetAsync(zbase, 0, zbytes, stream);

  k_prep1<<<34, 256, 0, stream>>>(W2, b2, Wq, Wk, Wv, Wq2, Wk2, Wv2,
                                  Wqp, Wkp, bqp, bkp, Wvsp, bvs, dhd, wv2s);
  k_prep2<<<17, 256, 0, stream>>>(Wqp, Wkp, bqp, MBpk, c2th);
  k_front<<<nEdgeB + nPairB + nNodeB, 256, 0, stream>>>(
      x, eidx, ea, W1, b1, Wvsp, bvs, embB, vsb,
      e2e, pcnt, pbucket, n2n, ncnt, nbucket,
      E, EE, C, N, nEdgeB, nPairB);
  k_back<<<nPairMfmaB + nNodeSegB, 256, 0, stream>>>(
      embB, MBpk, vsb, c2th, pcnt, pbucket, ncnt, nbucket,
      x, dhd, wv2s, out0, out1, E, N, nPairMfmaB);
}

// Round 9
// 306.625 us; speedup vs baseline: 1.1518x; 1.1518x over previous
//
#include <hip/hip_runtime.h>
#include <stdint.h>

#define HIDN 128
#define EMBN 32
#define PCAP 16        // pair bucket row (Poisson(2): overflow ~0)
#define NCAP 64        // node bucket row (Poisson(16): overflow ~0)
#define PSEGSH 10      // pair bin = ed >> 10  (1024 segs/bin)
#define NSEGSH 7       // node bin = nd >> 7   (128 nodes/bin)
#define PSEG (1 << PSEGSH)
#define NSEG (1 << NSEGSH)
#define PBCAP 2816     // entries/pair-bin cap (mean 2048, sigma~45)
#define NBCAP 2816     // entries/node-bin cap (mean 2048)
#define CHUNK 4096     // items per partition block (16/thread)
#define MAXBINS 400

typedef __attribute__((ext_vector_type(8))) short bf16x8;
typedef __attribute__((ext_vector_type(4))) float f32x4;
typedef unsigned long long u64;

// ---------- helpers ----------
__device__ __forceinline__ unsigned bf16r(float f) {   // fp32 -> bf16 bits, RNE
  unsigned u = __float_as_uint(f);
  return (u + 0x7FFFu + ((u >> 16) & 1u)) >> 16;
}
__device__ __forceinline__ unsigned pack2(float a, float b) {  // a -> low16, b -> high16
  return bf16r(a) | (bf16r(b) << 16);
}
__device__ __forceinline__ float blo(unsigned u) { return __uint_as_float(u << 16); }
__device__ __forceinline__ float bhi(unsigned u) { return __uint_as_float(u & 0xFFFF0000u); }
__device__ __forceinline__ float4 f4fma(float s, float4 a, float4 b) {
  return make_float4(fmaf(s, a.x, b.x), fmaf(s, a.y, b.y), fmaf(s, a.z, b.z), fmaf(s, a.w, b.w));
}
__device__ __forceinline__ float4 f4max0(float4 a) {
  return make_float4(fmaxf(a.x, 0.f), fmaxf(a.y, 0.f), fmaxf(a.z, 0.f), fmaxf(a.w, 0.f));
}

// ---------- prep1: Wq'=W2@Wq, Wk'=W2@Wk, biases, Wvsp/bvs, dhd, wv2s ----------
__global__ __launch_bounds__(256) void k_prep1(
    const float* __restrict__ W2, const float* __restrict__ b2,
    const float* __restrict__ Wq, const float* __restrict__ Wk, const float* __restrict__ Wv,
    const float* __restrict__ Wq2, const float* __restrict__ Wk2, const float* __restrict__ Wv2,
    float* __restrict__ Wqp, float* __restrict__ Wkp,
    float* __restrict__ bqp, float* __restrict__ bkp,
    float* __restrict__ Wvsp, float* __restrict__ bvs,
    float* __restrict__ dhd, float* __restrict__ wv2s)
{
  const float rs = 0.17677669529663687f;  // 1/sqrt(32)
  int idx = blockIdx.x * 256 + threadIdx.x;
  if (idx < 8192) {
    int q = idx < 4096;
    int t = q ? idx : idx - 4096;
    int i = t >> 7, j = t & 127;
    const float* W = q ? Wq : Wk;
    float a = 0.f;
    for (int l = 0; l < HIDN; l++)
      a = fmaf(W2[i * HIDN + l], W[l * HIDN + j], a);
    (q ? Wqp : Wkp)[t] = a;
  } else if (idx < 8448) {
    int q = idx < 8320;
    int j = (q ? idx - 8192 : idx - 8320);
    const float* W = q ? Wq : Wk;
    float a = 0.f;
    for (int l = 0; l < HIDN; l++)
      a = fmaf(b2[l], W[l * HIDN + j], a);
    (q ? bqp : bkp)[j] = a;
  } else if (idx < 8576) {
    int t = idx - 8448;
    int i = t >> 2, h = t & 3;
    float a = 0.f;
    for (int l = 0; l < HIDN; l++) {
      float s = 0.f;
      const float* wl = Wv + l * HIDN + h * 32;
      for (int dh = 0; dh < 32; dh++) s += wl[dh];
      a = fmaf(W2[i * HIDN + l], s, a);
    }
    Wvsp[t] = a;
  } else if (idx < 8580) {
    int h = idx - 8576;
    float a = 0.f;
    for (int l = 0; l < HIDN; l++) {
      float s = 0.f;
      const float* wl = Wv + l * HIDN + h * 32;
      for (int dh = 0; dh < 32; dh++) s += wl[dh];
      a = fmaf(b2[l], s, a);
    }
    bvs[h] = a;
  } else if (idx < 8584) {
    int h = idx - 8580;
    float d = 0.f, wsum = 0.f;
    for (int dh = 0; dh < 32; dh++) {
      d = fmaf(Wq2[h * 32 + dh], Wk2[h * 32 + dh], d);
      wsum += Wv2[h * 32 + dh];
    }
    dhd[h]  = d * rs;
    wv2s[h] = wsum;
  }
}

// ---------- prep2: MBpk fragments + c2th ----------
__global__ __launch_bounds__(256) void k_prep2(
    const float* __restrict__ Wqp, const float* __restrict__ Wkp,
    const float* __restrict__ bqp,
    unsigned short* __restrict__ MBpk, float* __restrict__ c2th)
{
  const float rs = 0.17677669529663687f;
  int idx = blockIdx.x * 256 + threadIdx.x;
  if (idx < 4096) {
    int jj = idx & 7, lane = (idx >> 3) & 63, nb = (idx >> 9) & 1, h = idx >> 10;
    int k = (lane >> 4) * 8 + jj;
    int n = nb * 16 + (lane & 15);
    float a = 0.f;
    const float* wq = Wqp + k * HIDN + h * 32;
    const float* wk = Wkp + n * HIDN + h * 32;
    for (int j = 0; j < 32; j++) a = fmaf(wq[j], wk[j], a);
    MBpk[idx] = (unsigned short)bf16r(a * rs);
  } else if (idx < 4224) {
    int t = idx - 4096;
    int h = t >> 5, ip = t & 31;
    float a2 = 0.f;
    for (int j = 0; j < 32; j++)
      a2 = fmaf(bqp[h * 32 + j], Wkp[ip * HIDN + h * 32 + j], a2);
    c2th[h * 32 + ip] = a2 * rs;
  }
}

// ---------- K_front: edge MLP + LDS multi-split partition (pairs, nodes) ----------
__global__ __launch_bounds__(256, 4) void k_front(
    const float* __restrict__ x, const int* __restrict__ eidx, const float* __restrict__ ea,
    const float* __restrict__ W1, const float* __restrict__ b1,
    const float* __restrict__ Wvsp, const float* __restrict__ bvs,
    unsigned* __restrict__ embB, uint2* __restrict__ vsb,
    const int* __restrict__ e2e, int* __restrict__ goffP, u64* __restrict__ partP,
    const int* __restrict__ n2n, int* __restrict__ goffN, u64* __restrict__ partN,
    int E, int EE, int C, int N, int nEdgeB, int nPartP, int PBINS, int NBINS)
{
  __shared__ int lcnt[MAXBINS];
  __shared__ int lbase[MAXBINS];
  int b = blockIdx.x;
  int tid = threadIdx.x;
  if (b < nEdgeB) {
    // ----- edge MLP path (identical to r6) -----
    int e = b * 256 + tid;
    if (e >= E) return;
    int si = eidx[e], di = eidx[E + e];
    float xs = x[si], xd = x[di];

    const float4* b4  = (const float4*)b1;
    const float4* w0  = (const float4*)W1;
    const float4* w1r = (const float4*)(W1 + 32);
    float4 E0, E1, E2, E3, E4, E5, E6, E7;
#define INIT(i) E##i = f4fma(xs, w0[i], f4fma(xd, w1r[i], b4[i]));
    INIT(0) INIT(1) INIT(2) INIT(3) INIT(4) INIT(5) INIT(6) INIT(7)
#undef INIT
    const float4* ea4 = (const float4*)(ea + (size_t)e * 32);
#define ROW(c, wr) { const float4* w_ = (const float4*)(W1 + (size_t)(wr) * 32); \
  E0 = f4fma(c, w_[0], E0); E1 = f4fma(c, w_[1], E1); E2 = f4fma(c, w_[2], E2); E3 = f4fma(c, w_[3], E3); \
  E4 = f4fma(c, w_[4], E4); E5 = f4fma(c, w_[5], E5); E6 = f4fma(c, w_[6], E6); E7 = f4fma(c, w_[7], E7); }
#pragma unroll
    for (int rb = 0; rb < 8; rb++) {
      float4 v = ea4[rb];
      ROW(v.x, 2 + rb * 4 + 0)
      ROW(v.y, 2 + rb * 4 + 1)
      ROW(v.z, 2 + rb * 4 + 2)
      ROW(v.w, 2 + rb * 4 + 3)
    }
#undef ROW
    E0 = f4max0(E0); E1 = f4max0(E1); E2 = f4max0(E2); E3 = f4max0(E3);
    E4 = f4max0(E4); E5 = f4max0(E5); E6 = f4max0(E6); E7 = f4max0(E7);

    uint4 p0, p1, p2, p3;
    p0.x = pack2(E0.x, E0.y); p0.y = pack2(E0.z, E0.w); p0.z = pack2(E1.x, E1.y); p0.w = pack2(E1.z, E1.w);
    p1.x = pack2(E2.x, E2.y); p1.y = pack2(E2.z, E2.w); p1.z = pack2(E3.x, E3.y); p1.w = pack2(E3.z, E3.w);
    p2.x = pack2(E4.x, E4.y); p2.y = pack2(E4.z, E4.w); p2.z = pack2(E5.x, E5.y); p2.w = pack2(E5.z, E5.w);
    p3.x = pack2(E6.x, E6.y); p3.y = pack2(E6.z, E6.w); p3.z = pack2(E7.x, E7.y); p3.w = pack2(E7.z, E7.w);
    uint4* er = (uint4*)(embB + (size_t)e * 16);
    er[0] = p0; er[1] = p1; er[2] = p2; er[3] = p3;

    const float4* wv = (const float4*)Wvsp;
    float4 vs = *(const float4*)bvs;
#define VK(k) { vs = f4fma(E##k.x, wv[4*k+0], vs); vs = f4fma(E##k.y, wv[4*k+1], vs); \
                vs = f4fma(E##k.z, wv[4*k+2], vs); vs = f4fma(E##k.w, wv[4*k+3], vs); }
    VK(0) VK(1) VK(2) VK(3) VK(4) VK(5) VK(6) VK(7)
#undef VK
    vsb[e] = make_uint2(pack2(vs.x, vs.y), pack2(vs.z, vs.w));
  } else if (b < nEdgeB + nPartP) {
    // ----- pair partition: multi-split CHUNK pairs by ed>>PSEGSH -----
    int start = (b - nEdgeB) * CHUNK;
    for (int i = tid; i < PBINS; i += 256) lcnt[i] = 0;
    __syncthreads();
#pragma unroll 4
    for (int k = 0; k < 16; k++) {
      int p = start + k * 256 + tid;
      if (p < EE) atomicAdd(&lcnt[e2e[EE + p] >> PSEGSH], 1);
    }
    __syncthreads();
    for (int i = tid; i < PBINS; i += 256) {
      int c = lcnt[i];
      lbase[i] = c ? atomicAdd(&goffP[i], c) : 0;
      lcnt[i] = 0;
    }
    __syncthreads();
#pragma unroll 4
    for (int k = 0; k < 16; k++) {
      int p = start + k * 256 + tid;
      if (p < EE) {
        int es = e2e[p], ed = e2e[EE + p];
        int bin = ed >> PSEGSH;
        int pos = atomicAdd(&lcnt[bin], 1) + lbase[bin];
        if (pos < PBCAP)
          partP[(size_t)bin * PBCAP + pos] = ((u64)(unsigned)ed << 32) | (unsigned)es;
      }
    }
  } else {
    // ----- node partition: multi-split CHUNK entries by nd>>NSEGSH, payload asv=x[ns] -----
    int start = (b - nEdgeB - nPartP) * CHUNK;
    for (int i = tid; i < NBINS; i += 256) lcnt[i] = 0;
    __syncthreads();
#pragma unroll 4
    for (int k = 0; k < 16; k++) {
      int c = start + k * 256 + tid;
      if (c < C) {
        int nd = n2n[C + c];
        if (nd < N) atomicAdd(&lcnt[nd >> NSEGSH], 1);
      }
    }
    __syncthreads();
    for (int i = tid; i < NBINS; i += 256) {
      int c = lcnt[i];
      lbase[i] = c ? atomicAdd(&goffN[i], c) : 0;
      lcnt[i] = 0;
    }
    __syncthreads();
#pragma unroll 4
    for (int k = 0; k < 16; k++) {
      int c = start + k * 256 + tid;
      if (c < C) {
        int ns = n2n[c], nd = n2n[C + c];
        if (nd < N) {
          int bin = nd >> NSEGSH;
          unsigned pay = __float_as_uint(x[ns]);
          int pos = atomicAdd(&lcnt[bin], 1) + lbase[bin];
          if (pos < NBCAP)
            partN[(size_t)bin * NBCAP + pos] = ((u64)(unsigned)nd << 32) | pay;
        }
      }
    }
  }
}

// ---------- K_fill: per-bin bucket build in LDS, fully coalesced writes ----------
__global__ __launch_bounds__(256) void k_fill(
    const int* __restrict__ goffP, const u64* __restrict__ partP,
    const int* __restrict__ goffN, const u64* __restrict__ partN,
    int* __restrict__ pcnt, int* __restrict__ pbucket,
    int* __restrict__ ncnt, int* __restrict__ nbucket,
    int E, int N, int PBINS)
{
  extern __shared__ int lds[];   // pair: [PSEG cnt][PSEG*PCAP rows] = 69632 B
  int b = blockIdx.x;
  int tid = threadIdx.x;
  if (b < PBINS) {
    int seg0 = b << PSEGSH;
    int nseg = E - seg0; if (nseg > PSEG) nseg = PSEG;
    int* cnt = lds;
    int* rows = lds + PSEG;
    for (int i = tid; i < nseg; i += 256) cnt[i] = 0;
    __syncthreads();
    int g = goffP[b]; if (g > PBCAP) g = PBCAP;
    for (int i = tid; i < g; i += 256) {
      u64 pk = partP[(size_t)b * PBCAP + i];
      int ed = (int)(pk >> 32);
      int es = (int)(unsigned)pk;
      int s = ed - seg0;
      int pos = atomicAdd(&cnt[s], 1);
      if (pos < PCAP) rows[s * PCAP + pos] = es;
    }
    __syncthreads();
    for (int i = tid; i < nseg; i += 256) pcnt[seg0 + i] = cnt[i];
    int tot = nseg * PCAP;
    for (int i = tid; i < tot; i += 256)
      pbucket[(size_t)seg0 * PCAP + i] = rows[i];
  } else {
    int nb = b - PBINS;
    int seg0 = nb << NSEGSH;
    int nseg = N - seg0; if (nseg > NSEG) nseg = NSEG;
    int* cnt = lds;
    int* rows = lds + NSEG;
    for (int i = tid; i < nseg; i += 256) cnt[i] = 0;
    __syncthreads();
    int g = goffN[nb]; if (g > NBCAP) g = NBCAP;
    for (int i = tid; i < g; i += 256) {
      u64 pk = partN[(size_t)nb * NBCAP + i];
      int nd = (int)(pk >> 32);
      int pay = (int)(unsigned)pk;
      int s = nd - seg0;
      int pos = atomicAdd(&cnt[s], 1);
      if (pos < NCAP) rows[s * NCAP + pos] = pay;
    }
    __syncthreads();
    for (int i = tid; i < nseg; i += 256) ncnt[seg0 + i] = cnt[i];
    int tot = nseg * NCAP;
    for (int i = tid; i < tot; i += 256)
      nbucket[(size_t)seg0 * NCAP + i] = rows[i];
  }
}

// ---------- K_back: MFMA qt-transform + pair softmax, node softmax (r6 verbatim) ----------
__global__ __launch_bounds__(256, 4) void k_back(
    const unsigned* __restrict__ embB, const unsigned short* __restrict__ MBpk,
    const uint2* __restrict__ vsb, const float* __restrict__ c2th,
    const int* __restrict__ pcnt, const int* __restrict__ pbucket,
    const int* __restrict__ ncnt, const float* __restrict__ nbucket,
    const float* __restrict__ x, const float* __restrict__ dhd, const float* __restrict__ wv2s,
    float* __restrict__ out0, float* __restrict__ out1,
    int E, int N, int nPairB)
{
  __shared__ float qtl[256 * 33];
  int b = blockIdx.x;
  int tid = threadIdx.x;
  if (b < nPairB) {
    int wave = tid >> 6, lane = tid & 63;
    int e0 = b * 64;
    int we0 = e0 + wave * 16;

    union { uint4 u; bf16x8 bv; } af;
    af.u = *((const uint4*)(embB + ((size_t)(we0 + (lane & 15)) << 4)) + (lane >> 4));

#pragma unroll
    for (int h = 0; h < 4; h++) {
#pragma unroll
      for (int nb = 0; nb < 2; nb++) {
        union { uint4 u; bf16x8 bv; } bf;
        bf.u = *(const uint4*)(MBpk + (((h * 2 + nb) * 64 + lane) << 3));
        int col = nb * 16 + (lane & 15);
        float c2v = c2th[h * 32 + col];
        f32x4 acc = {c2v, c2v, c2v, c2v};
        acc = __builtin_amdgcn_mfma_f32_16x16x32_bf16(af.bv, bf.bv, acc, 0, 0, 0);
        int rowb = wave * 16 + (lane >> 4) * 4;
#pragma unroll
        for (int r = 0; r < 4; r++)
          qtl[((rowb + r) * 4 + h) * 33 + col] = acc[r];
      }
    }
    __syncthreads();

    int e = e0 + (tid >> 2);
    if (e >= E) return;
    int h = tid & 3;
    const float* q = qtl + tid * 33;

    int cnt = pcnt[e];
    cnt = cnt < PCAP ? cnt : PCAP;
    float den = 0.f, num = 0.f;
    for (int n = 0; n < cnt; n++) {
      int es = pbucket[(size_t)e * PCAP + n];
      const uint4* ep = (const uint4*)(embB + ((size_t)es << 4));
      uint4 u0 = ep[0], u1 = ep[1], u2 = ep[2], u3 = ep[3];
      uint2 vu = vsb[es];
      unsigned vh = (h & 2) ? vu.y : vu.x;
      float vsv = (h & 1) ? bhi(vh) : blo(vh);
      float dot = 0.f;
#define DOT8(uu, base) \
      dot = fmaf(q[base + 0], blo(uu.x), dot); dot = fmaf(q[base + 1], bhi(uu.x), dot); \
      dot = fmaf(q[base + 2], blo(uu.y), dot); dot = fmaf(q[base + 3], bhi(uu.y), dot); \
      dot = fmaf(q[base + 4], blo(uu.z), dot); dot = fmaf(q[base + 5], bhi(uu.z), dot); \
      dot = fmaf(q[base + 6], blo(uu.w), dot); dot = fmaf(q[base + 7], bhi(uu.w), dot);
      DOT8(u0, 0) DOT8(u1, 8) DOT8(u2, 16) DOT8(u3, 24)
#undef DOT8
      float ex = __expf(dot);
      den += ex;
      num = fmaf(ex, vsv, num);
    }
    float r = num / (den + 1e-16f);
    r += __shfl_xor(r, 1);
    r += __shfl_xor(r, 2);
    if (h == 0) out1[e] = r * 0.0078125f;   // 1/128
  } else {
    int idx = (b - nPairB) * 256 + tid;
    int nd = idx >> 2;
    if (nd >= N) return;
    int h = idx & 3;
    int cnt = ncnt[nd];
    cnt = cnt < NCAP ? cnt : NCAP;
    const float* bkt = nbucket + (size_t)nd * NCAP;
    float xn = x[nd];
    float d = dhd[h];

    float amx = -3.4e38f, amn = 3.4e38f;
    for (int n = 0; n < cnt; n++) {
      float a = xn * bkt[n];
      amx = fmaxf(amx, a); amn = fminf(amn, a);
    }
    float m = (d > 0.f) ? d * amx : d * amn;

    float den = 0.f, num = 0.f;
    for (int n = 0; n < cnt; n++) {
      float asv = bkt[n];
      float ev = __expf(fmaf(xn * asv, d, -m));
      den += ev;
      num = fmaf(ev, asv, num);
    }
    float r = wv2s[h] * num / (den + 1e-16f);
    r += __shfl_xor(r, 1);
    r += __shfl_xor(r, 2);
    if (h == 0) out0[nd] = r * 0.0078125f;   // 1/128
  }
}

extern "C" void kernel_launch(void* const* d_in, const int* in_sizes, int n_in,
                              void* d_out, int out_size, void* d_ws, size_t ws_size,
                              hipStream_t stream)
{
  const float* x   = (const float*)d_in[0];
  const int*   eidx= (const int*)d_in[1];
  const float* ea  = (const float*)d_in[2];
  const int*   e2e = (const int*)d_in[3];
  const int*   n2n = (const int*)d_in[4];
  const float* W1  = (const float*)d_in[5];
  const float* b1  = (const float*)d_in[6];
  const float* W2  = (const float*)d_in[7];
  const float* b2  = (const float*)d_in[8];
  const float* Wq  = (const float*)d_in[9];
  const float* Wk  = (const float*)d_in[10];
  const float* Wv  = (const float*)d_in[11];
  const float* Wq2 = (const float*)d_in[12];
  const float* Wk2 = (const float*)d_in[13];
  const float* Wv2 = (const float*)d_in[14];

  const int N  = in_sizes[0];        // x is [N,1]
  const int E  = in_sizes[1] / 2;
  const int EE = in_sizes[3] / 2;
  const int C  = in_sizes[4] / 2;

  float* out0 = (float*)d_out;       // [N]
  float* out1 = (float*)d_out + N;   // [E]

  const int PBINS = (E + PSEG - 1) >> PSEGSH;   // 391 for E=400k
  const int NBINS = (N + NSEG - 1) >> NSEGSH;   // 391 for N=50k

  char* w = (char*)d_ws;
  size_t off = 0;
  auto alloc = [&](size_t bytes) -> char* {
    char* p = w + off;
    off += (bytes + 255) & ~(size_t)255;
    return p;
  };
  float* Wqp   = (float*)alloc(EMBN * HIDN * 4);
  float* Wkp   = (float*)alloc(EMBN * HIDN * 4);
  float* bqp   = (float*)alloc(HIDN * 4);
  float* bkp   = (float*)alloc(HIDN * 4);
  unsigned short* MBpk = (unsigned short*)alloc(4096 * 2);
  float* c2th  = (float*)alloc(4 * EMBN * 4);
  float* Wvsp  = (float*)alloc(EMBN * 4 * 4);
  float* bvs   = (float*)alloc(16);
  float* dhd   = (float*)alloc(16);
  float* wv2s  = (float*)alloc(16);
  unsigned* embB = (unsigned*)alloc((size_t)E * 16 * 4);        // 25.6 MB
  uint2* vsb   = (uint2*)alloc((size_t)E * 8);                  // 3.2 MB
  u64*   partP = (u64*)alloc((size_t)PBINS * PBCAP * 8);        // 8.8 MB
  u64*   partN = (u64*)alloc((size_t)NBINS * NBCAP * 8);        // 8.8 MB
  int*   pbucket = (int*)alloc((size_t)E * PCAP * 4);           // 25.6 MB
  int*   nbucket = (int*)alloc((size_t)N * NCAP * 4);           // 12.8 MB
  int*   pcnt  = (int*)alloc((size_t)E * 4);                    // written by k_fill
  int*   ncnt  = (int*)alloc((size_t)N * 4);
  char* zbase = w + off;                                        // --- zeroed (bin offsets) ---
  int*   goffP = (int*)alloc((size_t)PBINS * 4);
  int*   goffN = (int*)alloc((size_t)NBINS * 4);
  size_t zbytes = (size_t)((w + off) - zbase);

  const int nEdgeB = (E + 255) / 256;
  const int nPartP = (EE + CHUNK - 1) / CHUNK;
  const int nPartN = (C + CHUNK - 1) / CHUNK;
  const int nPairMfmaB = (E + 63) / 64;
  const int nNodeSegB  = (N * 4 + 255) / 256;
  const size_t fillLDS = (size_t)(PSEG + PSEG * PCAP) * 4;   // 69632 B

  hipMemsetAsync(zbase, 0, zbytes, stream);

  k_prep1<<<34, 256, 0, stream>>>(W2, b2, Wq, Wk, Wv, Wq2, Wk2, Wv2,
                                  Wqp, Wkp, bqp, bkp, Wvsp, bvs, dhd, wv2s);
  k_prep2<<<17, 256, 0, stream>>>(Wqp, Wkp, bqp, MBpk, c2th);
  k_front<<<nEdgeB + nPartP + nPartN, 256, 0, stream>>>(
      x, eidx, ea, W1, b1, Wvsp, bvs, embB, vsb,
      e2e, goffP, partP, n2n, goffN, partN,
      E, EE, C, N, nEdgeB, nPartP, PBINS, NBINS);
  k_fill<<<PBINS + NBINS, 256, fillLDS, stream>>>(
      goffP, partP, goffN, partN, pcnt, pbucket, ncnt, nbucket, E, N, PBINS);
  k_back<<<nPairMfmaB + nNodeSegB, 256, 0, stream>>>(
      embB, MBpk, vsb, c2th, pcnt, pbucket, ncnt, (const float*)nbucket,
      x, dhd, wv2s, out0, out1, E, N, nPairMfmaB);
}

// Round 10
// 260.405 us; speedup vs baseline: 1.3562x; 1.1775x over previous
//
#include <hip/hip_runtime.h>
#include <stdint.h>

#define HIDN 128
#define EMBN 32
#define PCAP 16        // pair bucket row (Poisson(2): overflow ~0)
#define NCAP 64        // node bucket row (Poisson(16): overflow ~0)
#define PSEGSH 10      // pair bin = ed >> 10  (1024 segs/bin)
#define NSEGSH 7       // node bin = nd >> 7   (128 nodes/bin)
#define PSEG (1 << PSEGSH)
#define NSEG (1 << NSEGSH)
#define PBCAP 2816     // entries/pair-bin cap (mean 2048, sigma~45)
#define NBCAP 2816     // entries/node-bin cap (mean 2048)
#define CHUNK 4096     // items per partition block (16/thread)
#define MAXBINS 400

typedef __attribute__((ext_vector_type(8))) short bf16x8;
typedef __attribute__((ext_vector_type(4))) float f32x4;
typedef unsigned long long u64;

// ---------- helpers ----------
__device__ __forceinline__ unsigned bf16r(float f) {   // fp32 -> bf16 bits, RNE
  unsigned u = __float_as_uint(f);
  return (u + 0x7FFFu + ((u >> 16) & 1u)) >> 16;
}
__device__ __forceinline__ unsigned pack2(float a, float b) {  // a -> low16, b -> high16
  return bf16r(a) | (bf16r(b) << 16);
}
__device__ __forceinline__ float blo(unsigned u) { return __uint_as_float(u << 16); }
__device__ __forceinline__ float bhi(unsigned u) { return __uint_as_float(u & 0xFFFF0000u); }
__device__ __forceinline__ float4 f4fma(float s, float4 a, float4 b) {
  return make_float4(fmaf(s, a.x, b.x), fmaf(s, a.y, b.y), fmaf(s, a.z, b.z), fmaf(s, a.w, b.w));
}
__device__ __forceinline__ float4 f4max0(float4 a) {
  return make_float4(fmaxf(a.x, 0.f), fmaxf(a.y, 0.f), fmaxf(a.z, 0.f), fmaxf(a.w, 0.f));
}

// ---------- prep1 (r6 structure): Wq'=W2@Wq, Wk'=W2@Wk, biases, wvs ----------
// items: [0,4096) Wqp; [4096,8192) Wkp; [8192,8320) bqp; [8320,8448) bkp; [8448,8960) wvs
__global__ __launch_bounds__(256) void k_prep1(
    const float* __restrict__ W2, const float* __restrict__ b2,
    const float* __restrict__ Wq, const float* __restrict__ Wk, const float* __restrict__ Wv,
    float* __restrict__ Wqp, float* __restrict__ Wkp,
    float* __restrict__ bqp, float* __restrict__ bkp,
    float* __restrict__ wvs)
{
  int idx = blockIdx.x * 256 + threadIdx.x;
  if (idx < 8192) {
    int q = idx < 4096;
    int t = q ? idx : idx - 4096;
    int i = t >> 7, j = t & 127;
    const float* W = q ? Wq : Wk;
    float a = 0.f;
    for (int l = 0; l < HIDN; l++)
      a = fmaf(W2[i * HIDN + l], W[l * HIDN + j], a);
    (q ? Wqp : Wkp)[t] = a;
  } else if (idx < 8448) {
    int q = idx < 8320;
    int j = (q ? idx - 8192 : idx - 8320);
    const float* W = q ? Wq : Wk;
    float a = 0.f;
    for (int l = 0; l < HIDN; l++)
      a = fmaf(b2[l], W[l * HIDN + j], a);
    (q ? bqp : bkp)[j] = a;
  } else if (idx < 8960) {
    int t = idx - 8448;             // wvs[l*4+h] = sum_dh Wv[l][h*32+dh]
    int l = t >> 2, h = t & 3;
    float s = 0.f;
    for (int dh = 0; dh < 32; dh++) s += Wv[l * HIDN + h * 32 + dh];
    wvs[t] = s;
  }
}

// ---------- prep2 (r6 structure): MBpk, c2th, Wvsp, bvs, dhd, wv2s ----------
// items: [0,4096) MBpk; [4096,4224) c2th; [4224,4352) Wvsp; [4352,4356) scalars
__global__ __launch_bounds__(256) void k_prep2(
    const float* __restrict__ W2, const float* __restrict__ b2,
    const float* __restrict__ Wq2, const float* __restrict__ Wk2, const float* __restrict__ Wv2,
    const float* __restrict__ Wqp, const float* __restrict__ Wkp,
    const float* __restrict__ bqp, const float* __restrict__ wvs,
    unsigned short* __restrict__ MBpk,  // [4][2][64][8] bf16 B-frags of M_h (scaled)
    float* __restrict__ c2th,   // [4][32]
    float* __restrict__ Wvsp,   // [32][4]
    float* __restrict__ bvs, float* __restrict__ dhd, float* __restrict__ wv2s)
{
  const float rs = 0.17677669529663687f;  // 1/sqrt(32)
  int idx = blockIdx.x * 256 + threadIdx.x;
  if (idx < 4096) {
    // B[k=(lane>>4)*8+jj][n=nb*16+(lane&15)], element jj of lane's short8
    int jj = idx & 7, lane = (idx >> 3) & 63, nb = (idx >> 9) & 1, h = idx >> 10;
    int k = (lane >> 4) * 8 + jj;
    int n = nb * 16 + (lane & 15);
    float a = 0.f;
    const float* wq = Wqp + k * HIDN + h * 32;
    const float* wk = Wkp + n * HIDN + h * 32;
    for (int j = 0; j < 32; j++) a = fmaf(wq[j], wk[j], a);
    MBpk[idx] = (unsigned short)bf16r(a * rs);
  } else if (idx < 4224) {
    int t = idx - 4096;
    int h = t >> 5, ip = t & 31;
    float a2 = 0.f;
    for (int j = 0; j < 32; j++)
      a2 = fmaf(bqp[h * 32 + j], Wkp[ip * HIDN + h * 32 + j], a2);
    c2th[h * 32 + ip] = a2 * rs;
  } else if (idx < 4352) {
    int t = idx - 4224;
    int i = t >> 2, h = t & 3;
    float a = 0.f;
    for (int l = 0; l < HIDN; l++) a = fmaf(W2[i * HIDN + l], wvs[l * 4 + h], a);
    Wvsp[t] = a;
  } else if (idx < 4356) {
    int h = idx - 4352;
    float a = 0.f;
    for (int l = 0; l < HIDN; l++) a = fmaf(b2[l], wvs[l * 4 + h], a);
    bvs[h] = a;
    float d = 0.f, wsum = 0.f;
    for (int dh = 0; dh < 32; dh++) {
      d = fmaf(Wq2[h * 32 + dh], Wk2[h * 32 + dh], d);
      wsum += Wv2[h * 32 + dh];
    }
    dhd[h]  = d * rs;
    wv2s[h] = wsum;
  }
}

// ---------- K_front: edge MLP + LDS multi-split partition (pairs, nodes) ----------
__global__ __launch_bounds__(256, 4) void k_front(
    const float* __restrict__ x, const int* __restrict__ eidx, const float* __restrict__ ea,
    const float* __restrict__ W1, const float* __restrict__ b1,
    const float* __restrict__ Wvsp, const float* __restrict__ bvs,
    unsigned* __restrict__ embB, uint2* __restrict__ vsb,
    const int* __restrict__ e2e, int* __restrict__ goffP, u64* __restrict__ partP,
    const int* __restrict__ n2n, int* __restrict__ goffN, u64* __restrict__ partN,
    int E, int EE, int C, int N, int nEdgeB, int nPartP, int PBINS, int NBINS)
{
  __shared__ int lcnt[MAXBINS];
  __shared__ int lbase[MAXBINS];
  int b = blockIdx.x;
  int tid = threadIdx.x;
  if (b < nEdgeB) {
    // ----- edge MLP path -----
    int e = b * 256 + tid;
    if (e >= E) return;
    int si = eidx[e], di = eidx[E + e];
    float xs = x[si], xd = x[di];

    const float4* b4  = (const float4*)b1;
    const float4* w0  = (const float4*)W1;
    const float4* w1r = (const float4*)(W1 + 32);
    float4 E0, E1, E2, E3, E4, E5, E6, E7;
#define INIT(i) E##i = f4fma(xs, w0[i], f4fma(xd, w1r[i], b4[i]));
    INIT(0) INIT(1) INIT(2) INIT(3) INIT(4) INIT(5) INIT(6) INIT(7)
#undef INIT
    const float4* ea4 = (const float4*)(ea + (size_t)e * 32);
#define ROW(c, wr) { const float4* w_ = (const float4*)(W1 + (size_t)(wr) * 32); \
  E0 = f4fma(c, w_[0], E0); E1 = f4fma(c, w_[1], E1); E2 = f4fma(c, w_[2], E2); E3 = f4fma(c, w_[3], E3); \
  E4 = f4fma(c, w_[4], E4); E5 = f4fma(c, w_[5], E5); E6 = f4fma(c, w_[6], E6); E7 = f4fma(c, w_[7], E7); }
#pragma unroll
    for (int rb = 0; rb < 8; rb++) {
      float4 v = ea4[rb];
      ROW(v.x, 2 + rb * 4 + 0)
      ROW(v.y, 2 + rb * 4 + 1)
      ROW(v.z, 2 + rb * 4 + 2)
      ROW(v.w, 2 + rb * 4 + 3)
    }
#undef ROW
    E0 = f4max0(E0); E1 = f4max0(E1); E2 = f4max0(E2); E3 = f4max0(E3);
    E4 = f4max0(E4); E5 = f4max0(E5); E6 = f4max0(E6); E7 = f4max0(E7);

    uint4 p0, p1, p2, p3;
    p0.x = pack2(E0.x, E0.y); p0.y = pack2(E0.z, E0.w); p0.z = pack2(E1.x, E1.y); p0.w = pack2(E1.z, E1.w);
    p1.x = pack2(E2.x, E2.y); p1.y = pack2(E2.z, E2.w); p1.z = pack2(E3.x, E3.y); p1.w = pack2(E3.z, E3.w);
    p2.x = pack2(E4.x, E4.y); p2.y = pack2(E4.z, E4.w); p2.z = pack2(E5.x, E5.y); p2.w = pack2(E5.z, E5.w);
    p3.x = pack2(E6.x, E6.y); p3.y = pack2(E6.z, E6.w); p3.z = pack2(E7.x, E7.y); p3.w = pack2(E7.z, E7.w);
    uint4* er = (uint4*)(embB + (size_t)e * 16);
    er[0] = p0; er[1] = p1; er[2] = p2; er[3] = p3;

    const float4* wv = (const float4*)Wvsp;
    float4 vs = *(const float4*)bvs;
#define VK(k) { vs = f4fma(E##k.x, wv[4*k+0], vs); vs = f4fma(E##k.y, wv[4*k+1], vs); \
                vs = f4fma(E##k.z, wv[4*k+2], vs); vs = f4fma(E##k.w, wv[4*k+3], vs); }
    VK(0) VK(1) VK(2) VK(3) VK(4) VK(5) VK(6) VK(7)
#undef VK
    vsb[e] = make_uint2(pack2(vs.x, vs.y), pack2(vs.z, vs.w));
  } else if (b < nEdgeB + nPartP) {
    // ----- pair partition: multi-split CHUNK pairs by ed>>PSEGSH -----
    int start = (b - nEdgeB) * CHUNK;
    for (int i = tid; i < PBINS; i += 256) lcnt[i] = 0;
    __syncthreads();
#pragma unroll 4
    for (int k = 0; k < 16; k++) {
      int p = start + k * 256 + tid;
      if (p < EE) atomicAdd(&lcnt[e2e[EE + p] >> PSEGSH], 1);
    }
    __syncthreads();
    for (int i = tid; i < PBINS; i += 256) {
      int c = lcnt[i];
      lbase[i] = c ? atomicAdd(&goffP[i], c) : 0;
      lcnt[i] = 0;
    }
    __syncthreads();
#pragma unroll 4
    for (int k = 0; k < 16; k++) {
      int p = start + k * 256 + tid;
      if (p < EE) {
        int es = e2e[p], ed = e2e[EE + p];
        int bin = ed >> PSEGSH;
        int pos = atomicAdd(&lcnt[bin], 1) + lbase[bin];
        if (pos < PBCAP)
          partP[(size_t)bin * PBCAP + pos] = ((u64)(unsigned)ed << 32) | (unsigned)es;
      }
    }
  } else {
    // ----- node partition: multi-split CHUNK entries by nd>>NSEGSH, payload asv=x[ns] -----
    int start = (b - nEdgeB - nPartP) * CHUNK;
    for (int i = tid; i < NBINS; i += 256) lcnt[i] = 0;
    __syncthreads();
#pragma unroll 4
    for (int k = 0; k < 16; k++) {
      int c = start + k * 256 + tid;
      if (c < C) {
        int nd = n2n[C + c];
        if (nd < N) atomicAdd(&lcnt[nd >> NSEGSH], 1);
      }
    }
    __syncthreads();
    for (int i = tid; i < NBINS; i += 256) {
      int c = lcnt[i];
      lbase[i] = c ? atomicAdd(&goffN[i], c) : 0;
      lcnt[i] = 0;
    }
    __syncthreads();
#pragma unroll 4
    for (int k = 0; k < 16; k++) {
      int c = start + k * 256 + tid;
      if (c < C) {
        int ns = n2n[c], nd = n2n[C + c];
        if (nd < N) {
          int bin = nd >> NSEGSH;
          unsigned pay = __float_as_uint(x[ns]);
          int pos = atomicAdd(&lcnt[bin], 1) + lbase[bin];
          if (pos < NBCAP)
            partN[(size_t)bin * NBCAP + pos] = ((u64)(unsigned)nd << 32) | pay;
        }
      }
    }
  }
}

// ---------- K_fill: per-bin bucket build in LDS, fully coalesced writes ----------
__global__ __launch_bounds__(256) void k_fill(
    const int* __restrict__ goffP, const u64* __restrict__ partP,
    const int* __restrict__ goffN, const u64* __restrict__ partN,
    int* __restrict__ pcnt, int* __restrict__ pbucket,
    int* __restrict__ ncnt, int* __restrict__ nbucket,
    int E, int N, int PBINS)
{
  extern __shared__ int lds[];   // pair: [PSEG cnt][PSEG*PCAP rows] = 69632 B
  int b = blockIdx.x;
  int tid = threadIdx.x;
  if (b < PBINS) {
    int seg0 = b << PSEGSH;
    int nseg = E - seg0; if (nseg > PSEG) nseg = PSEG;
    int* cnt = lds;
    int* rows = lds + PSEG;
    for (int i = tid; i < nseg; i += 256) cnt[i] = 0;
    __syncthreads();
    int g = goffP[b]; if (g > PBCAP) g = PBCAP;
    for (int i = tid; i < g; i += 256) {
      u64 pk = partP[(size_t)b * PBCAP + i];
      int ed = (int)(pk >> 32);
      int es = (int)(unsigned)pk;
      int s = ed - seg0;
      int pos = atomicAdd(&cnt[s], 1);
      if (pos < PCAP) rows[s * PCAP + pos] = es;
    }
    __syncthreads();
    for (int i = tid; i < nseg; i += 256) pcnt[seg0 + i] = cnt[i];
    int tot = nseg * PCAP;
    for (int i = tid; i < tot; i += 256)
      pbucket[(size_t)seg0 * PCAP + i] = rows[i];
  } else {
    int nb = b - PBINS;
    int seg0 = nb << NSEGSH;
    int nseg = N - seg0; if (nseg > NSEG) nseg = NSEG;
    int* cnt = lds;
    int* rows = lds + NSEG;
    for (int i = tid; i < nseg; i += 256) cnt[i] = 0;
    __syncthreads();
    int g = goffN[nb]; if (g > NBCAP) g = NBCAP;
    for (int i = tid; i < g; i += 256) {
      u64 pk = partN[(size_t)nb * NBCAP + i];
      int nd = (int)(pk >> 32);
      int pay = (int)(unsigned)pk;
      int s = nd - seg0;
      int pos = atomicAdd(&cnt[s], 1);
      if (pos < NCAP) rows[s * NCAP + pos] = pay;
    }
    __syncthreads();
    for (int i = tid; i < nseg; i += 256) ncnt[seg0 + i] = cnt[i];
    int tot = nseg * NCAP;
    for (int i = tid; i < tot; i += 256)
      nbucket[(size_t)seg0 * NCAP + i] = rows[i];
  }
}

// ---------- K_back: MFMA qt-transform + pair softmax, node softmax ----------
__global__ __launch_bounds__(256, 4) void k_back(
    const unsigned* __restrict__ embB, const unsigned short* __restrict__ MBpk,
    const uint2* __restrict__ vsb, const float* __restrict__ c2th,
    const int* __restrict__ pcnt, const int* __restrict__ pbucket,
    const int* __restrict__ ncnt, const float* __restrict__ nbucket,
    const float* __restrict__ x, const float* __restrict__ dhd, const float* __restrict__ wv2s,
    float* __restrict__ out0, float* __restrict__ out1,
    int E, int N, int nPairB)
{
  __shared__ float qtl[256 * 33];
  int b = blockIdx.x;
  int tid = threadIdx.x;
  if (b < nPairB) {
    int wave = tid >> 6, lane = tid & 63;
    int e0 = b * 64;
    int we0 = e0 + wave * 16;

    union { uint4 u; bf16x8 bv; } af;
    af.u = *((const uint4*)(embB + ((size_t)(we0 + (lane & 15)) << 4)) + (lane >> 4));

#pragma unroll
    for (int h = 0; h < 4; h++) {
#pragma unroll
      for (int nb = 0; nb < 2; nb++) {
        union { uint4 u; bf16x8 bv; } bf;
        bf.u = *(const uint4*)(MBpk + (((h * 2 + nb) * 64 + lane) << 3));
        int col = nb * 16 + (lane & 15);
        float c2v = c2th[h * 32 + col];
        f32x4 acc = {c2v, c2v, c2v, c2v};
        acc = __builtin_amdgcn_mfma_f32_16x16x32_bf16(af.bv, bf.bv, acc, 0, 0, 0);
        int rowb = wave * 16 + (lane >> 4) * 4;
#pragma unroll
        for (int r = 0; r < 4; r++)
          qtl[((rowb + r) * 4 + h) * 33 + col] = acc[r];
      }
    }
    __syncthreads();

    int e = e0 + (tid >> 2);
    if (e >= E) return;
    int h = tid & 3;
    const float* q = qtl + tid * 33;

    int cnt = pcnt[e];
    cnt = cnt < PCAP ? cnt : PCAP;
    float den = 0.f, num = 0.f;
    for (int n = 0; n < cnt; n++) {
      int es = pbucket[(size_t)e * PCAP + n];
      const uint4* ep = (const uint4*)(embB + ((size_t)es << 4));
      uint4 u0 = ep[0], u1 = ep[1], u2 = ep[2], u3 = ep[3];
      uint2 vu = vsb[es];
      unsigned vh = (h & 2) ? vu.y : vu.x;
      float vsv = (h & 1) ? bhi(vh) : blo(vh);
      float dot = 0.f;
#define DOT8(uu, base) \
      dot = fmaf(q[base + 0], blo(uu.x), dot); dot = fmaf(q[base + 1], bhi(uu.x), dot); \
      dot = fmaf(q[base + 2], blo(uu.y), dot); dot = fmaf(q[base + 3], bhi(uu.y), dot); \
      dot = fmaf(q[base + 4], blo(uu.z), dot); dot = fmaf(q[base + 5], bhi(uu.z), dot); \
      dot = fmaf(q[base + 6], blo(uu.w), dot); dot = fmaf(q[base + 7], bhi(uu.w), dot);
      DOT8(u0, 0) DOT8(u1, 8) DOT8(u2, 16) DOT8(u3, 24)
#undef DOT8
      float ex = __expf(dot);
      den += ex;
      num = fmaf(ex, vsv, num);
    }
    float r = num / (den + 1e-16f);
    r += __shfl_xor(r, 1);
    r += __shfl_xor(r, 2);
    if (h == 0) out1[e] = r * 0.0078125f;   // 1/128
  } else {
    int idx = (b - nPairB) * 256 + tid;
    int nd = idx >> 2;
    if (nd >= N) return;
    int h = idx & 3;
    int cnt = ncnt[nd];
    cnt = cnt < NCAP ? cnt : NCAP;
    const float* bkt = nbucket + (size_t)nd * NCAP;
    float xn = x[nd];
    float d = dhd[h];

    float amx = -3.4e38f, amn = 3.4e38f;
    for (int n = 0; n < cnt; n++) {
      float a = xn * bkt[n];
      amx = fmaxf(amx, a); amn = fminf(amn, a);
    }
    float m = (d > 0.f) ? d * amx : d * amn;

    float den = 0.f, num = 0.f;
    for (int n = 0; n < cnt; n++) {
      float asv = bkt[n];
      float ev = __expf(fmaf(xn * asv, d, -m));
      den += ev;
      num = fmaf(ev, asv, num);
    }
    float r = wv2s[h] * num / (den + 1e-16f);
    r += __shfl_xor(r, 1);
    r += __shfl_xor(r, 2);
    if (h == 0) out0[nd] = r * 0.0078125f;   // 1/128
  }
}

extern "C" void kernel_launch(void* const* d_in, const int* in_sizes, int n_in,
                              void* d_out, int out_size, void* d_ws, size_t ws_size,
                              hipStream_t stream)
{
  const float* x   = (const float*)d_in[0];
  const int*   eidx= (const int*)d_in[1];
  const float* ea  = (const float*)d_in[2];
  const int*   e2e = (const int*)d_in[3];
  const int*   n2n = (const int*)d_in[4];
  const float* W1  = (const float*)d_in[5];
  const float* b1  = (const float*)d_in[6];
  const float* W2  = (const float*)d_in[7];
  const float* b2  = (const float*)d_in[8];
  const float* Wq  = (const float*)d_in[9];
  const float* Wk  = (const float*)d_in[10];
  const float* Wv  = (const float*)d_in[11];
  const float* Wq2 = (const float*)d_in[12];
  const float* Wk2 = (const float*)d_in[13];
  const float* Wv2 = (const float*)d_in[14];

  const int N  = in_sizes[0];        // x is [N,1]
  const int E  = in_sizes[1] / 2;
  const int EE = in_sizes[3] / 2;
  const int C  = in_sizes[4] / 2;

  float* out0 = (float*)d_out;       // [N]
  float* out1 = (float*)d_out + N;   // [E]

  const int PBINS = (E + PSEG - 1) >> PSEGSH;   // 391 for E=400k
  const int NBINS = (N + NSEG - 1) >> NSEGSH;   // 391 for N=50k

  char* w = (char*)d_ws;
  size_t off = 0;
  auto alloc = [&](size_t bytes) -> char* {
    char* p = w + off;
    off += (bytes + 255) & ~(size_t)255;
    return p;
  };
  float* Wqp   = (float*)alloc(EMBN * HIDN * 4);
  float* Wkp   = (float*)alloc(EMBN * HIDN * 4);
  float* bqp   = (float*)alloc(HIDN * 4);
  float* bkp   = (float*)alloc(HIDN * 4);
  float* wvs   = (float*)alloc(HIDN * 4 * 4);
  unsigned short* MBpk = (unsigned short*)alloc(4096 * 2);
  float* c2th  = (float*)alloc(4 * EMBN * 4);
  float* Wvsp  = (float*)alloc(EMBN * 4 * 4);
  float* bvs   = (float*)alloc(16);
  float* dhd   = (float*)alloc(16);
  float* wv2s  = (float*)alloc(16);
  unsigned* embB = (unsigned*)alloc((size_t)E * 16 * 4);        // 25.6 MB
  uint2* vsb   = (uint2*)alloc((size_t)E * 8);                  // 3.2 MB
  u64*   partP = (u64*)alloc((size_t)PBINS * PBCAP * 8);        // 8.8 MB
  u64*   partN = (u64*)alloc((size_t)NBINS * NBCAP * 8);        // 8.8 MB
  int*   pbucket = (int*)alloc((size_t)E * PCAP * 4);           // 25.6 MB
  int*   nbucket = (int*)alloc((size_t)N * NCAP * 4);           // 12.8 MB
  int*   pcnt  = (int*)alloc((size_t)E * 4);                    // written by k_fill
  int*   ncnt  = (int*)alloc((size_t)N * 4);
  char* zbase = w + off;                                        // --- zeroed (bin offsets) ---
  int*   goffP = (int*)alloc((size_t)PBINS * 4);
  int*   goffN = (int*)alloc((size_t)NBINS * 4);
  size_t zbytes = (size_t)((w + off) - zbase);

  const int nEdgeB = (E + 255) / 256;
  const int nPartP = (EE + CHUNK - 1) / CHUNK;
  const int nPartN = (C + CHUNK - 1) / CHUNK;
  const int nPairMfmaB = (E + 63) / 64;
  const int nNodeSegB  = (N * 4 + 255) / 256;
  const size_t fillLDS = (size_t)(PSEG + PSEG * PCAP) * 4;   // 69632 B

  hipMemsetAsync(zbase, 0, zbytes, stream);

  k_prep1<<<35, 256, 0, stream>>>(W2, b2, Wq, Wk, Wv, Wqp, Wkp, bqp, bkp, wvs);
  k_prep2<<<18, 256, 0, stream>>>(W2, b2, Wq2, Wk2, Wv2, Wqp, Wkp, bqp, wvs,
                                  MBpk, c2th, Wvsp, bvs, dhd, wv2s);
  k_front<<<nEdgeB + nPartP + nPartN, 256, 0, stream>>>(
      x, eidx, ea, W1, b1, Wvsp, bvs, embB, vsb,
      e2e, goffP, partP, n2n, goffN, partN,
      E, EE, C, N, nEdgeB, nPartP, PBINS, NBINS);
  k_fill<<<PBINS + NBINS, 256, fillLDS, stream>>>(
      goffP, partP, goffN, partN, pcnt, pbucket, ncnt, nbucket, E, N, PBINS);
  k_back<<<nPairMfmaB + nNodeSegB, 256, 0, stream>>>(
      embB, MBpk, vsb, c2th, pcnt, pbucket, ncnt, (const float*)nbucket,
      x, dhd, wv2s, out0, out1, E, N, nPairMfmaB);
}

// Round 11
// 232.772 us; speedup vs baseline: 1.5172x; 1.1187x over previous
//
#include <hip/hip_runtime.h>
#include <stdint.h>

#define HIDN 128
#define EMBN 32
#define PCAP 16        // pair bucket row (Poisson(2): overflow ~0)
#define NCAP 64        // node bucket row (Poisson(16): overflow ~0)
#define PSEGSH 10      // pair bin = ed >> 10  (1024 segs/bin)
#define NSEGSH 7       // node bin = nd >> 7   (128 nodes/bin)
#define PSEG (1 << PSEGSH)
#define NSEG (1 << NSEGSH)
#define PBCAP 2816     // entries/pair-bin cap (mean 2048)
#define NBCAP 2816     // entries/node-bin cap (mean 2048)
#define CHUNK 2048     // items per partition block (8/thread)
#define MAXBINS 400

typedef __attribute__((ext_vector_type(8))) short bf16x8;
typedef __attribute__((ext_vector_type(4))) float f32x4;
typedef unsigned long long u64;

// ---------- helpers ----------
__device__ __forceinline__ unsigned bf16r(float f) {   // fp32 -> bf16 bits, RNE
  unsigned u = __float_as_uint(f);
  return (u + 0x7FFFu + ((u >> 16) & 1u)) >> 16;
}
__device__ __forceinline__ unsigned pack2(float a, float b) {
  return bf16r(a) | (bf16r(b) << 16);
}
__device__ __forceinline__ float blo(unsigned u) { return __uint_as_float(u << 16); }
__device__ __forceinline__ float bhi(unsigned u) { return __uint_as_float(u & 0xFFFF0000u); }
__device__ __forceinline__ float4 f4fma(float s, float4 a, float4 b) {
  return make_float4(fmaf(s, a.x, b.x), fmaf(s, a.y, b.y), fmaf(s, a.z, b.z), fmaf(s, a.w, b.w));
}
__device__ __forceinline__ float4 f4max0(float4 a) {
  return make_float4(fmaxf(a.x, 0.f), fmaxf(a.y, 0.f), fmaxf(a.z, 0.f), fmaxf(a.w, 0.f));
}

// ---------- prep1: Wq'=W2@Wq, Wk'=W2@Wk, bqp; block 33: Wvsp/bvs via LDS two-phase ----------
__global__ __launch_bounds__(256) void k_prep1(
    const float* __restrict__ W2, const float* __restrict__ b2,
    const float* __restrict__ Wq, const float* __restrict__ Wk, const float* __restrict__ Wv,
    float* __restrict__ Wqp, float* __restrict__ Wkp, float* __restrict__ bqp,
    float* __restrict__ Wvsp, float* __restrict__ bvs)
{
  __shared__ float swvs[HIDN * 4];
  int t = threadIdx.x;
  if (blockIdx.x == 33) {
    // phase A: swvs[l][h] = sum_dh Wv[l][h*32+dh]
    for (int idx = t; idx < HIDN * 4; idx += 256) {
      int l = idx >> 2, h = idx & 3;
      float s = 0.f;
      const float* wl = Wv + l * HIDN + h * 32;
      for (int dh = 0; dh < 32; dh++) s += wl[dh];
      swvs[idx] = s;
    }
    __syncthreads();
    if (t < 128) {
      int i = t >> 2, h = t & 3;
      float a = 0.f;
      for (int l = 0; l < HIDN; l++) a = fmaf(W2[i * HIDN + l], swvs[l * 4 + h], a);
      Wvsp[t] = a;
    } else if (t < 132) {
      int h = t - 128;
      float a = 0.f;
      for (int l = 0; l < HIDN; l++) a = fmaf(b2[l], swvs[l * 4 + h], a);
      bvs[h] = a;
    }
    return;
  }
  int idx = blockIdx.x * 256 + t;
  if (idx < 8192) {
    int q = idx < 4096;
    int tt = q ? idx : idx - 4096;
    int i = tt >> 7, j = tt & 127;
    const float* W = q ? Wq : Wk;
    float a = 0.f;
    for (int l = 0; l < HIDN; l++)
      a = fmaf(W2[i * HIDN + l], W[l * HIDN + j], a);
    (q ? Wqp : Wkp)[tt] = a;
  } else if (idx < 8320) {
    int j = idx - 8192;
    float a = 0.f;
    for (int l = 0; l < HIDN; l++)
      a = fmaf(b2[l], Wq[l * HIDN + j], a);
    bqp[j] = a;
  }
}

// ---------- K_front: edge MLP + LDS multi-split partition (pairs, nodes) ----------
__global__ __launch_bounds__(256, 4) void k_front(
    const float* __restrict__ x, const int* __restrict__ eidx, const float* __restrict__ ea,
    const float* __restrict__ W1, const float* __restrict__ b1,
    const float* __restrict__ Wvsp, const float* __restrict__ bvs,
    unsigned* __restrict__ embB, uint2* __restrict__ vsb,
    const int* __restrict__ e2e, int* __restrict__ goffP, u64* __restrict__ partP,
    const int* __restrict__ n2n, int* __restrict__ goffN, u64* __restrict__ partN,
    int E, int EE, int C, int N, int nEdgeB, int nPartP, int PBINS, int NBINS)
{
  __shared__ int lcnt[MAXBINS];
  __shared__ int lbase[MAXBINS];
  int b = blockIdx.x;
  int tid = threadIdx.x;
  if (b < nEdgeB) {
    // ----- edge MLP path -----
    int e = b * 256 + tid;
    if (e >= E) return;
    int si = eidx[e], di = eidx[E + e];
    float xs = x[si], xd = x[di];

    const float4* b4  = (const float4*)b1;
    const float4* w0  = (const float4*)W1;
    const float4* w1r = (const float4*)(W1 + 32);
    float4 E0, E1, E2, E3, E4, E5, E6, E7;
#define INIT(i) E##i = f4fma(xs, w0[i], f4fma(xd, w1r[i], b4[i]));
    INIT(0) INIT(1) INIT(2) INIT(3) INIT(4) INIT(5) INIT(6) INIT(7)
#undef INIT
    const float4* ea4 = (const float4*)(ea + (size_t)e * 32);
#define ROW(c, wr) { const float4* w_ = (const float4*)(W1 + (size_t)(wr) * 32); \
  E0 = f4fma(c, w_[0], E0); E1 = f4fma(c, w_[1], E1); E2 = f4fma(c, w_[2], E2); E3 = f4fma(c, w_[3], E3); \
  E4 = f4fma(c, w_[4], E4); E5 = f4fma(c, w_[5], E5); E6 = f4fma(c, w_[6], E6); E7 = f4fma(c, w_[7], E7); }
#pragma unroll
    for (int rb = 0; rb < 8; rb++) {
      float4 v = ea4[rb];
      ROW(v.x, 2 + rb * 4 + 0)
      ROW(v.y, 2 + rb * 4 + 1)
      ROW(v.z, 2 + rb * 4 + 2)
      ROW(v.w, 2 + rb * 4 + 3)
    }
#undef ROW
    E0 = f4max0(E0); E1 = f4max0(E1); E2 = f4max0(E2); E3 = f4max0(E3);
    E4 = f4max0(E4); E5 = f4max0(E5); E6 = f4max0(E6); E7 = f4max0(E7);

    uint4 p0, p1, p2, p3;
    p0.x = pack2(E0.x, E0.y); p0.y = pack2(E0.z, E0.w); p0.z = pack2(E1.x, E1.y); p0.w = pack2(E1.z, E1.w);
    p1.x = pack2(E2.x, E2.y); p1.y = pack2(E2.z, E2.w); p1.z = pack2(E3.x, E3.y); p1.w = pack2(E3.z, E3.w);
    p2.x = pack2(E4.x, E4.y); p2.y = pack2(E4.z, E4.w); p2.z = pack2(E5.x, E5.y); p2.w = pack2(E5.z, E5.w);
    p3.x = pack2(E6.x, E6.y); p3.y = pack2(E6.z, E6.w); p3.z = pack2(E7.x, E7.y); p3.w = pack2(E7.z, E7.w);
    uint4* er = (uint4*)(embB + (size_t)e * 16);
    er[0] = p0; er[1] = p1; er[2] = p2; er[3] = p3;

    const float4* wv = (const float4*)Wvsp;
    float4 vs = *(const float4*)bvs;
#define VK(k) { vs = f4fma(E##k.x, wv[4*k+0], vs); vs = f4fma(E##k.y, wv[4*k+1], vs); \
                vs = f4fma(E##k.z, wv[4*k+2], vs); vs = f4fma(E##k.w, wv[4*k+3], vs); }
    VK(0) VK(1) VK(2) VK(3) VK(4) VK(5) VK(6) VK(7)
#undef VK
    vsb[e] = make_uint2(pack2(vs.x, vs.y), pack2(vs.z, vs.w));
  } else if (b < nEdgeB + nPartP) {
    // ----- pair partition: multi-split CHUNK pairs by ed>>PSEGSH -----
    int start = (b - nEdgeB) * CHUNK;
    for (int i = tid; i < PBINS; i += 256) lcnt[i] = 0;
    __syncthreads();
#pragma unroll 4
    for (int k = 0; k < 8; k++) {
      int p = start + k * 256 + tid;
      if (p < EE) atomicAdd(&lcnt[e2e[EE + p] >> PSEGSH], 1);
    }
    __syncthreads();
    for (int i = tid; i < PBINS; i += 256) {
      int c = lcnt[i];
      lbase[i] = c ? atomicAdd(&goffP[i], c) : 0;
      lcnt[i] = 0;
    }
    __syncthreads();
#pragma unroll 4
    for (int k = 0; k < 8; k++) {
      int p = start + k * 256 + tid;
      if (p < EE) {
        int es = e2e[p], ed = e2e[EE + p];
        int bin = ed >> PSEGSH;
        int pos = atomicAdd(&lcnt[bin], 1) + lbase[bin];
        if (pos < PBCAP)
          partP[(size_t)bin * PBCAP + pos] = ((u64)(unsigned)ed << 32) | (unsigned)es;
      }
    }
  } else {
    // ----- node partition: multi-split CHUNK entries by nd>>NSEGSH, payload asv=x[ns] -----
    int start = (b - nEdgeB - nPartP) * CHUNK;
    for (int i = tid; i < NBINS; i += 256) lcnt[i] = 0;
    __syncthreads();
#pragma unroll 4
    for (int k = 0; k < 8; k++) {
      int c = start + k * 256 + tid;
      if (c < C) {
        int nd = n2n[C + c];
        if (nd < N) atomicAdd(&lcnt[nd >> NSEGSH], 1);
      }
    }
    __syncthreads();
    for (int i = tid; i < NBINS; i += 256) {
      int c = lcnt[i];
      lbase[i] = c ? atomicAdd(&goffN[i], c) : 0;
      lcnt[i] = 0;
    }
    __syncthreads();
#pragma unroll 4
    for (int k = 0; k < 8; k++) {
      int c = start + k * 256 + tid;
      if (c < C) {
        int ns = n2n[c], nd = n2n[C + c];
        if (nd < N) {
          int bin = nd >> NSEGSH;
          unsigned pay = __float_as_uint(x[ns]);
          int pos = atomicAdd(&lcnt[bin], 1) + lbase[bin];
          if (pos < NBCAP)
            partN[(size_t)bin * NBCAP + pos] = ((u64)(unsigned)nd << 32) | pay;
        }
      }
    }
  }
}

// ---------- K_fill: pair bucket build in LDS + prep2 tail blocks (MBpk, c2th, scalars) ----------
__global__ __launch_bounds__(256) void k_fill(
    const int* __restrict__ goffP, const u64* __restrict__ partP,
    int* __restrict__ pcnt, int* __restrict__ pbucket,
    const float* __restrict__ Wqp, const float* __restrict__ Wkp,
    const float* __restrict__ bqp,
    const float* __restrict__ Wq2, const float* __restrict__ Wk2, const float* __restrict__ Wv2,
    unsigned short* __restrict__ MBpk, float* __restrict__ c2th,
    float* __restrict__ dhd, float* __restrict__ wv2s,
    int E, int PBINS)
{
  extern __shared__ int lds[];   // [PSEG cnt][PSEG*PCAP rows] = 69632 B
  const float rs = 0.17677669529663687f;  // 1/sqrt(32)
  int b = blockIdx.x;
  int tid = threadIdx.x;
  if (b < PBINS) {
    int seg0 = b << PSEGSH;
    int nseg = E - seg0; if (nseg > PSEG) nseg = PSEG;
    int* cnt = lds;
    int* rows = lds + PSEG;
    for (int i = tid; i < nseg; i += 256) cnt[i] = 0;
    __syncthreads();
    int g = goffP[b]; if (g > PBCAP) g = PBCAP;
    for (int i = tid; i < g; i += 256) {
      u64 pk = partP[(size_t)b * PBCAP + i];
      int ed = (int)(pk >> 32);
      int es = (int)(unsigned)pk;
      int s = ed - seg0;
      int pos = atomicAdd(&cnt[s], 1);
      if (pos < PCAP) rows[s * PCAP + pos] = es;
    }
    __syncthreads();
    for (int i = tid; i < nseg; i += 256) pcnt[seg0 + i] = cnt[i];
    int tot = nseg * PCAP;
    for (int i = tid; i < tot; i += 256)
      pbucket[(size_t)seg0 * PCAP + i] = rows[i];
  } else {
    // ----- prep2 path -----
    int idx = (b - PBINS) * 256 + tid;
    if (idx < 4096) {
      // B[k=(lane>>4)*8+jj][n=nb*16+(lane&15)], element jj of lane's short8
      int jj = idx & 7, lane = (idx >> 3) & 63, nb = (idx >> 9) & 1, h = idx >> 10;
      int k = (lane >> 4) * 8 + jj;
      int n = nb * 16 + (lane & 15);
      float a = 0.f;
      const float* wq = Wqp + k * HIDN + h * 32;
      const float* wk = Wkp + n * HIDN + h * 32;
      for (int j = 0; j < 32; j++) a = fmaf(wq[j], wk[j], a);
      MBpk[idx] = (unsigned short)bf16r(a * rs);
    } else if (idx < 4224) {
      int t = idx - 4096;
      int h = t >> 5, ip = t & 31;
      float a2 = 0.f;
      for (int j = 0; j < 32; j++)
        a2 = fmaf(bqp[h * 32 + j], Wkp[ip * HIDN + h * 32 + j], a2);
      c2th[h * 32 + ip] = a2 * rs;
    } else if (idx < 4228) {
      int h = idx - 4224;
      float d = 0.f, wsum = 0.f;
      for (int dh = 0; dh < 32; dh++) {
        d = fmaf(Wq2[h * 32 + dh], Wk2[h * 32 + dh], d);
        wsum += Wv2[h * 32 + dh];
      }
      dhd[h]  = d * rs;
      wv2s[h] = wsum;
    }
  }
}

// ---------- K_back: node-bin softmax (LDS-staged) + MFMA qt-transform + pair softmax ----------
__global__ __launch_bounds__(256, 4) void k_back(
    const unsigned* __restrict__ embB, const unsigned short* __restrict__ MBpk,
    const uint2* __restrict__ vsb, const float* __restrict__ c2th,
    const int* __restrict__ pcnt, const int* __restrict__ pbucket,
    const int* __restrict__ goffN, const u64* __restrict__ partN,
    const float* __restrict__ x, const float* __restrict__ dhd, const float* __restrict__ wv2s,
    float* __restrict__ out0, float* __restrict__ out1,
    int E, int N, int NBINS)
{
  __shared__ float qtl[256 * 33];   // pair: qt tile; node: aliased as cnt+rows (8320 <= 8448)
  int b = blockIdx.x;
  int tid = threadIdx.x;
  if (b < NBINS) {
    // ----- node bin: stage partN into LDS bucket, then per-(node,head) softmax -----
    int seg0 = b << NSEGSH;
    int nseg = N - seg0; if (nseg > NSEG) nseg = NSEG;
    int* cnt = (int*)qtl;              // [NSEG]
    float* rows = qtl + NSEG;          // [NSEG * NCAP]
    for (int i = tid; i < nseg; i += 256) cnt[i] = 0;
    __syncthreads();
    int g = goffN[b]; if (g > NBCAP) g = NBCAP;
    for (int i = tid; i < g; i += 256) {
      u64 pk = partN[(size_t)b * NBCAP + i];
      int nd = (int)(pk >> 32);
      int s = nd - seg0;
      int pos = atomicAdd(&cnt[s], 1);
      if (pos < NCAP) rows[s * NCAP + pos] = __uint_as_float((unsigned)pk);
    }
    __syncthreads();
    for (int t = tid; t < nseg * 4; t += 256) {
      int s = t >> 2, h = t & 3;
      int c = cnt[s]; c = c < NCAP ? c : NCAP;
      int nd = seg0 + s;
      float xn = x[nd];
      float d = dhd[h];
      const float* bkt = rows + s * NCAP;

      float amx = -3.4e38f, amn = 3.4e38f;
      for (int n = 0; n < c; n++) {
        float a = xn * bkt[n];
        amx = fmaxf(amx, a); amn = fminf(amn, a);
      }
      float m = (d > 0.f) ? d * amx : d * amn;

      float den = 0.f, num = 0.f;
      for (int n = 0; n < c; n++) {
        float asv = bkt[n];
        float ev = __expf(fmaf(xn * asv, d, -m));
        den += ev;
        num = fmaf(ev, asv, num);
      }
      float r = wv2s[h] * num / (den + 1e-16f);
      r += __shfl_xor(r, 1);
      r += __shfl_xor(r, 2);
      if (h == 0) out0[nd] = r * 0.0078125f;   // 1/128
    }
  } else {
    // ----- pair path: MFMA qt into LDS, then bucket softmax per (e,h) -----
    int pb = b - NBINS;
    int wave = tid >> 6, lane = tid & 63;
    int e0 = pb * 64;
    int we0 = e0 + wave * 16;

    union { uint4 u; bf16x8 bv; } af;
    af.u = *((const uint4*)(embB + ((size_t)(we0 + (lane & 15)) << 4)) + (lane >> 4));

#pragma unroll
    for (int h = 0; h < 4; h++) {
#pragma unroll
      for (int nb = 0; nb < 2; nb++) {
        union { uint4 u; bf16x8 bv; } bf;
        bf.u = *(const uint4*)(MBpk + (((h * 2 + nb) * 64 + lane) << 3));
        int col = nb * 16 + (lane & 15);
        float c2v = c2th[h * 32 + col];
        f32x4 acc = {c2v, c2v, c2v, c2v};
        acc = __builtin_amdgcn_mfma_f32_16x16x32_bf16(af.bv, bf.bv, acc, 0, 0, 0);
        int rowb = wave * 16 + (lane >> 4) * 4;
#pragma unroll
        for (int r = 0; r < 4; r++)
          qtl[((rowb + r) * 4 + h) * 33 + col] = acc[r];
      }
    }
    __syncthreads();

    int e = e0 + (tid >> 2);
    if (e >= E) return;
    int h = tid & 3;
    const float* q = qtl + tid * 33;

    int cnt = pcnt[e];
    cnt = cnt < PCAP ? cnt : PCAP;
    float den = 0.f, num = 0.f;
    for (int n = 0; n < cnt; n++) {
      int es = pbucket[(size_t)e * PCAP + n];
      const uint4* ep = (const uint4*)(embB + ((size_t)es << 4));
      uint4 u0 = ep[0], u1 = ep[1], u2 = ep[2], u3 = ep[3];
      uint2 vu = vsb[es];
      unsigned vh = (h & 2) ? vu.y : vu.x;
      float vsv = (h & 1) ? bhi(vh) : blo(vh);
      float dot = 0.f;
#define DOT8(uu, base) \
      dot = fmaf(q[base + 0], blo(uu.x), dot); dot = fmaf(q[base + 1], bhi(uu.x), dot); \
      dot = fmaf(q[base + 2], blo(uu.y), dot); dot = fmaf(q[base + 3], bhi(uu.y), dot); \
      dot = fmaf(q[base + 4], blo(uu.z), dot); dot = fmaf(q[base + 5], bhi(uu.z), dot); \
      dot = fmaf(q[base + 6], blo(uu.w), dot); dot = fmaf(q[base + 7], bhi(uu.w), dot);
      DOT8(u0, 0) DOT8(u1, 8) DOT8(u2, 16) DOT8(u3, 24)
#undef DOT8
      float ex = __expf(dot);
      den += ex;
      num = fmaf(ex, vsv, num);
    }
    float r = num / (den + 1e-16f);
    r += __shfl_xor(r, 1);
    r += __shfl_xor(r, 2);
    if (h == 0) out1[e] = r * 0.0078125f;   // 1/128
  }
}

extern "C" void kernel_launch(void* const* d_in, const int* in_sizes, int n_in,
                              void* d_out, int out_size, void* d_ws, size_t ws_size,
                              hipStream_t stream)
{
  const float* x   = (const float*)d_in[0];
  const int*   eidx= (const int*)d_in[1];
  const float* ea  = (const float*)d_in[2];
  const int*   e2e = (const int*)d_in[3];
  const int*   n2n = (const int*)d_in[4];
  const float* W1  = (const float*)d_in[5];
  const float* b1  = (const float*)d_in[6];
  const float* W2  = (const float*)d_in[7];
  const float* b2  = (const float*)d_in[8];
  const float* Wq  = (const float*)d_in[9];
  const float* Wk  = (const float*)d_in[10];
  const float* Wv  = (const float*)d_in[11];
  const float* Wq2 = (const float*)d_in[12];
  const float* Wk2 = (const float*)d_in[13];
  const float* Wv2 = (const float*)d_in[14];

  const int N  = in_sizes[0];        // x is [N,1]
  const int E  = in_sizes[1] / 2;
  const int EE = in_sizes[3] / 2;
  const int C  = in_sizes[4] / 2;

  float* out0 = (float*)d_out;       // [N]
  float* out1 = (float*)d_out + N;   // [E]

  const int PBINS = (E + PSEG - 1) >> PSEGSH;   // 391 for E=400k
  const int NBINS = (N + NSEG - 1) >> NSEGSH;   // 391 for N=50k

  char* w = (char*)d_ws;
  size_t off = 0;
  auto alloc = [&](size_t bytes) -> char* {
    char* p = w + off;
    off += (bytes + 255) & ~(size_t)255;
    return p;
  };
  float* Wqp   = (float*)alloc(EMBN * HIDN * 4);
  float* Wkp   = (float*)alloc(EMBN * HIDN * 4);
  float* bqp   = (float*)alloc(HIDN * 4);
  unsigned short* MBpk = (unsigned short*)alloc(4096 * 2);
  float* c2th  = (float*)alloc(4 * EMBN * 4);
  float* Wvsp  = (float*)alloc(EMBN * 4 * 4);
  float* bvs   = (float*)alloc(16);
  float* dhd   = (float*)alloc(16);
  float* wv2s  = (float*)alloc(16);
  unsigned* embB = (unsigned*)alloc((size_t)E * 16 * 4);        // 25.6 MB
  uint2* vsb   = (uint2*)alloc((size_t)E * 8);                  // 3.2 MB
  u64*   partP = (u64*)alloc((size_t)PBINS * PBCAP * 8);        // 8.8 MB
  u64*   partN = (u64*)alloc((size_t)NBINS * NBCAP * 8);        // 8.8 MB
  int*   pbucket = (int*)alloc((size_t)E * PCAP * 4);           // 25.6 MB
  int*   pcnt  = (int*)alloc((size_t)E * 4);
  char* zbase = w + off;                                        // --- zeroed (bin offsets) ---
  int*   goffP = (int*)alloc((size_t)PBINS * 4);
  int*   goffN = (int*)alloc((size_t)NBINS * 4);
  size_t zbytes = (size_t)((w + off) - zbase);

  const int nEdgeB = (E + 255) / 256;
  const int nPartP = (EE + CHUNK - 1) / CHUNK;
  const int nPartN = (C + CHUNK - 1) / CHUNK;
  const int nPairMfmaB = (E + 63) / 64;
  const int nPrep2B = 17;                                    // 4228 items
  const size_t fillLDS = (size_t)(PSEG + PSEG * PCAP) * 4;   // 69632 B

  hipMemsetAsync(zbase, 0, zbytes, stream);

  k_prep1<<<34, 256, 0, stream>>>(W2, b2, Wq, Wk, Wv, Wqp, Wkp, bqp, Wvsp, bvs);
  k_front<<<nEdgeB + nPartP + nPartN, 256, 0, stream>>>(
      x, eidx, ea, W1, b1, Wvsp, bvs, embB, vsb,
      e2e, goffP, partP, n2n, goffN, partN,
      E, EE, C, N, nEdgeB, nPartP, PBINS, NBINS);
  k_fill<<<PBINS + nPrep2B, 256, fillLDS, stream>>>(
      goffP, partP, pcnt, pbucket,
      Wqp, Wkp, bqp, Wq2, Wk2, Wv2, MBpk, c2th, dhd, wv2s, E, PBINS);
  k_back<<<NBINS + nPairMfmaB, 256, 0, stream>>>(
      embB, MBpk, vsb, c2th, pcnt, pbucket, goffN, partN,
      x, dhd, wv2s, out0, out1, E, N, NBINS);
}